// Round 20
// baseline (147.816 us; speedup 1.0000x reference)
//
#include <hip/hip_runtime.h>
#include <hip/hip_bf16.h>
#include <stdint.h>

#define NROWS   65536
#define GR      16                // rows per group
#define NGRP    16                // groups per block
#define RPB     (GR*NGRP)         // 256 rows per block
#define NBLK    (NROWS/RPB)       // 256 blocks = 1 per CU
#define TPB     1024
#define H2N     100
#define KPAD    128
#define N3      1224
#define OUTW    2193
#define TAILN   969
#define NMAIN   77
#define PSTRC   2212              // panel row stride (shorts)

typedef __attribute__((ext_vector_type(8))) short bf16x8;
typedef __attribute__((ext_vector_type(4))) float f32x4;
typedef __attribute__((ext_vector_type(4))) unsigned short u16x4;

__device__ __forceinline__ float fast_sigmoid(float z){
    return __builtin_amdgcn_rcpf(1.0f + __expf(-z));
}
__device__ __forceinline__ unsigned short f2bf(float v){
    __hip_bfloat16 h = __float2bfloat16(v);
    return *reinterpret_cast<unsigned short*>(&h);
}
__device__ __forceinline__ float bf2f(unsigned short u){
    return __uint_as_float(((unsigned)u) << 16);
}
__device__ __forceinline__ void store16(float* p, f32x4 v){
    __builtin_memcpy(p, &v, 16);
}

// raw barrier: LDS-order only — does NOT drain outstanding global stores
#define BAR() do { asm volatile("s_waitcnt lgkmcnt(0)" ::: "memory");  \
                   __builtin_amdgcn_s_barrier();                        \
                   __builtin_amdgcn_sched_barrier(0); } while(0)

// blocks 0..76: w3f[((t*4+ks)*64+lane)*8+e] = bf16(W3[k][t*16+lm]), b3 folded at k==100.
// blocks 77..80: tail tables pk[p]=(c2<<16)|c1, pw[p]=w[j] (padded to 976).
__global__ void prep_kernel(const float* __restrict__ W3,
                            const float* __restrict__ b3,
                            const float* __restrict__ wgt,
                            const int* __restrict__ idx1,
                            const int* __restrict__ idx2,
                            unsigned short* __restrict__ w3f,
                            unsigned int* __restrict__ pk,
                            float* __restrict__ pw){
    const int blk = blockIdx.x;
    if (blk < NMAIN){
        const int ks   = threadIdx.x >> 6;
        const int lane = threadIdx.x & 63;
        const int lm   = lane & 15, lgf = lane >> 4;
        const int c    = blk * 16 + lm;
        const bool ok  = (c < N3);

        unsigned short vals[8];
        #pragma unroll
        for (int e = 0; e < 8; ++e){
            int k = ks * 32 + lgf * 8 + e;
            float v = 0.0f;
            if (ok){
                if (k < H2N)       v = W3[k * N3 + c];
                else if (k == H2N) v = b3[c];          // bias folded into K
            }
            vals[e] = f2bf(v);
        }
        *reinterpret_cast<bf16x8*>(w3f + ((size_t)(blk * 4 + ks) * 64 + lane) * 8)
            = *reinterpret_cast<bf16x8*>(vals);
    } else {
        const int p = (blk - NMAIN) * 256 + threadIdx.x;
        if (p < 976){
            if (p < TAILN){
                int j = p / 17, k = p - j * 17;
                pk[p] = ((unsigned)(idx2[j] * 17 + k) << 16) | (unsigned)(idx1[j] * 17 + k);
                pw[p] = wgt[j];
            } else { pk[p] = 0; pw[p] = 0.0f; }
        }
    }
}

__global__ __launch_bounds__(TPB, 4)
void snn_kernel(const float* __restrict__ x,
                const float* __restrict__ W1, const float* __restrict__ b1,
                const float* __restrict__ W2, const float* __restrict__ b2,
                const unsigned short* __restrict__ w3f,
                const unsigned int* __restrict__ pk,
                const float* __restrict__ pw,
                float* __restrict__ out)
{
    __shared__ __align__(16) unsigned short panel[2][GR][PSTRC];// 141,568 B (dbuf)
    __shared__ __align__(16) unsigned short h2b[GR][KPAD];      //   4,096 B
    __shared__ float w2s[H2N * 10];                             //   4,000 B
    __shared__ float b2s[H2N];                                  //     400 B
    __shared__ float xs[RPB];                                   //   1,024 B
    __shared__ float w1s[10], b1s[10];                          //      80 B
    __shared__ __align__(16) unsigned int pks[976];             //   3,904 B
    __shared__ __align__(16) float        pws[976];             //   3,904 B
    // total 158,976 B <= 163,840 -> 1 block/CU

    const int t = threadIdx.x, lane = t & 63, wid = t >> 6;     // 16 waves
    const int lm = lane & 15, lg = lane >> 4;
    const unsigned int rowblk0 = blockIdx.x * RPB;

    #define LOADFRAG(dst, tile) do {                                              \
        const unsigned short* bp_ = w3f + ((size_t)((tile) * 4) * 64 + lane) * 8; \
        _Pragma("unroll")                                                         \
        for (int ks_ = 0; ks_ < 4; ++ks_)                                         \
            dst[ks_] = *reinterpret_cast<const bf16x8*>(bp_ + (size_t)ks_ * 512); \
    } while(0)

    // one dump chunk: wave's own row of buffer `buf` -> 1 KB contiguous f32 store
    #define DUMPCHUNK(buf, orow, ch) do {                                         \
        const int rc_ = (ch) * 256 + (lane << 2);                                 \
        if (rc_ <= 2188){                                                         \
            const int vc_ = rc_ + (rc_ >= N3 ? 8 : 0);                            \
            const u16x4 pv_ = *reinterpret_cast<const u16x4*>(&panel[buf][wid][vc_]); \
            f32x4 v_;                                                             \
            _Pragma("unroll")                                                     \
            for (int e_ = 0; e_ < 4; ++e_) v_[e_] = bf2f(pv_[e_]);                \
            store16((orow) + rc_, v_);                                            \
        } else if (rc_ == 2192){                                                  \
            (orow)[rc_] = bf2f(panel[buf][wid][rc_ + 8]);                         \
        }                                                                         \
    } while(0)

    // ---- prologue: stage everything (the only global loads in this kernel)
    for (int i = t; i < H2N * 10; i += TPB) w2s[i] = W2[i];
    if (t < H2N) b2s[t] = b2[t];
    if (t < 10){ w1s[t] = W1[t]; b1s[t] = b1[t]; }
    if (t < RPB) xs[t] = x[rowblk0 + t];
    if (t < 976){ pks[t] = pk[t]; pws[t] = pw[t]; }

    bf16x8 wfr[5][4];                       // W3 frags resident (80 VGPR)
    #pragma unroll
    for (int i = 0; i < 5; ++i){
        const int s = wid + (i << 4);
        if (s < NMAIN) LOADFRAG(wfr[i], s);
    }
    __syncthreads();                        // one full sync (drains prologue loads)

    // ---- 16-group steady state: 2 raw barriers/group; dump(g-1) interleaved in B(g)
    for (int g = 0; g < NGRP; ++g){
        const int cur = g & 1, prv = cur ^ 1;
        // ---- A: fused h1+h2 — thread owns (row t>>6, cols c0,c0+1)
        {
            const int r  = t >> 6;
            const int c0 = (t & 63) << 1;
            const float xr = xs[(g << 4) + r];
            float h1v[10];
            #pragma unroll
            for (int j = 0; j < 10; ++j)
                h1v[j] = fast_sigmoid(xr * w1s[j] + b1s[j]);
            unsigned short o0, o1;
            if (c0 < H2N){
                float z = b2s[c0];
                #pragma unroll
                for (int j = 0; j < 10; ++j) z += h1v[j] * w2s[j * H2N + c0];
                o0 = f2bf(fast_sigmoid(z));
            } else o0 = (c0 == H2N) ? 0x3F80 : 0;
            const int c1 = c0 + 1;
            if (c1 < H2N){
                float z = b2s[c1];
                #pragma unroll
                for (int j = 0; j < 10; ++j) z += h1v[j] * w2s[j * H2N + c1];
                o1 = f2bf(fast_sigmoid(z));
            } else o1 = (c1 == H2N) ? 0x3F80 : 0;
            *reinterpret_cast<unsigned int*>(&h2b[t >> 6][c0]) =
                (unsigned)o0 | ((unsigned)o1 << 16);
        }
        BAR();                                             // BAR1: h2 ready
        // ---- B: MFMA -> panel[cur], with dump chunks of panel[prv] interleaved
        {
            bf16x8 hfr[4];
            #pragma unroll
            for (int ks = 0; ks < 4; ++ks)
                hfr[ks] = *reinterpret_cast<const bf16x8*>(&h2b[lm][ks * 32 + lg * 8]);
            float* orow = out + (size_t)(rowblk0 + ((g - 1) << 4) + wid) * OUTW;
            #pragma unroll
            for (int i = 0; i < 5; ++i){
                const int s = wid + (i << 4);
                if (s < NMAIN){
                    f32x4 a = {0,0,0,0};
                    #pragma unroll
                    for (int ks = 0; ks < 4; ++ks)
                        a = __builtin_amdgcn_mfma_f32_16x16x32_bf16(wfr[i][ks], hfr[ks], a, 0, 0, 0);
                    unsigned short o[4];
                    #pragma unroll
                    for (int r = 0; r < 4; ++r) o[r] = f2bf(fast_sigmoid(a[r]));
                    *reinterpret_cast<u16x4*>(&panel[cur][lm][(s << 4) + (lg << 2)]) =
                        *reinterpret_cast<u16x4*>(o);
                }
                if (g >= 1){                               // spread prev-row dump
                    DUMPCHUNK(prv, orow, 2 * i);
                    if (i < 4) DUMPCHUNK(prv, orow, 2 * i + 1);
                }
            }
        }
        BAR();                                             // BAR2: panel[cur] main cols ready
        // ---- C: tail lerp only — wave wid owns row wid of panel[cur]
        {
            const int row = wid;
            #pragma unroll
            for (int i = 0; i < 8; ++i){
                const int p0 = (lane + (i << 6)) << 1;     // even p, pair (p0, p0+1)
                if (p0 < TAILN){
                    const unsigned int k0 = pks[p0], k1 = pks[p0 + 1];
                    const float w0 = pws[p0], w1 = pws[p0 + 1];
                    const float a2 = bf2f(panel[cur][row][k0 >> 16]);
                    const float a1 = bf2f(panel[cur][row][k0 & 0xffffu]);
                    const float b2v = bf2f(panel[cur][row][k1 >> 16]);
                    const float b1v = bf2f(panel[cur][row][k1 & 0xffffu]);
                    const unsigned short t0 = f2bf(fmaf(w0, a1 - a2, a2));
                    const unsigned short t1 = f2bf(fmaf(w1, b1v - b2v, b2v));
                    *reinterpret_cast<unsigned int*>(&panel[cur][row][1232 + p0]) =
                        (unsigned)t0 | ((unsigned)t1 << 16);
                }
            }
        }
        // no trailing barrier: next BAR1 (lgkmcnt(0)+barrier) orders everything
    }

    // ---- epilogue: dump last group's panel
    asm volatile("s_waitcnt lgkmcnt(0)" ::: "memory");     // own C-writes visible to own reads
    {
        const int lastb = (NGRP - 1) & 1;
        float* orow = out + (size_t)(rowblk0 + ((NGRP - 1) << 4) + wid) * OUTW;
        #pragma unroll
        for (int ch = 0; ch < 9; ++ch)
            DUMPCHUNK(lastb, orow, ch);
    }
    #undef LOADFRAG
    #undef DUMPCHUNK
}

extern "C" void kernel_launch(void* const* d_in, const int* in_sizes, int n_in,
                              void* d_out, int out_size, void* d_ws, size_t ws_size,
                              hipStream_t stream)
{
    const float* x   = (const float*)d_in[0];
    const float* W1  = (const float*)d_in[1];
    const float* b1  = (const float*)d_in[2];
    const float* W2  = (const float*)d_in[3];
    const float* b2  = (const float*)d_in[4];
    const float* W3  = (const float*)d_in[5];
    const float* b3  = (const float*)d_in[6];
    const float* wgt = (const float*)d_in[7];
    const int*   i1  = (const int*)d_in[8];
    const int*   i2  = (const int*)d_in[9];
    float* out = (float*)d_out;

    unsigned char* ws = (unsigned char*)d_ws;
    unsigned short* w3f = (unsigned short*)ws;                 // 315,392 B
    unsigned int*   pk  = (unsigned int*)(ws + 315392);        // 3,904 B
    float*          pw  = (float*)(ws + 315392 + 3904);        // 3,904 B

    prep_kernel<<<NMAIN + 4, 256, 0, stream>>>(W3, b3, wgt, i1, i2, w3f, pk, pw);
    snn_kernel<<<NBLK, TPB, 0, stream>>>(x, W1, b1, W2, b2, w3f, pk, pw, out);
}

// Round 21
// 126.273 us; speedup vs baseline: 1.1706x; 1.1706x over previous
//
#include <hip/hip_runtime.h>
#include <hip/hip_bf16.h>
#include <stdint.h>

#define NROWS   65536
#define GR      16                // rows per group
#define NGRP    16                // groups per block
#define RPB     (GR*NGRP)         // 256 rows per block
#define NBLK    (NROWS/RPB)       // 256 blocks = 1 per CU
#define TPB     1024
#define H2N     100
#define KPAD    128
#define N3      1224
#define OUTW    2193
#define TAILN   969
#define NMAIN   77
#define PSTRC   2212              // panel row stride (shorts)

typedef __attribute__((ext_vector_type(8))) short bf16x8;
typedef __attribute__((ext_vector_type(4))) float f32x4;
typedef __attribute__((ext_vector_type(4))) unsigned short u16x4;

__device__ __forceinline__ float fast_sigmoid(float z){
    return __builtin_amdgcn_rcpf(1.0f + __expf(-z));
}
__device__ __forceinline__ unsigned short f2bf(float v){
    __hip_bfloat16 h = __float2bfloat16(v);
    return *reinterpret_cast<unsigned short*>(&h);
}
__device__ __forceinline__ float bf2f(unsigned short u){
    return __uint_as_float(((unsigned)u) << 16);
}
__device__ __forceinline__ void store16(float* p, f32x4 v){
    __builtin_memcpy(p, &v, 16);
}

// raw barrier: LDS-order only — does NOT drain outstanding global stores
#define BAR() do { asm volatile("s_waitcnt lgkmcnt(0)" ::: "memory");  \
                   __builtin_amdgcn_s_barrier();                        \
                   __builtin_amdgcn_sched_barrier(0); } while(0)

// blocks 0..76: w3f[((t*4+ks)*64+lane)*8+e] = bf16(W3[k][t*16+lm]), b3 folded at k==100.
// blocks 77..80: tail tables pk[p]=(c2<<16)|c1, pw[p]=w[j] (padded to 976).
__global__ void prep_kernel(const float* __restrict__ W3,
                            const float* __restrict__ b3,
                            const float* __restrict__ wgt,
                            const int* __restrict__ idx1,
                            const int* __restrict__ idx2,
                            unsigned short* __restrict__ w3f,
                            unsigned int* __restrict__ pk,
                            float* __restrict__ pw){
    const int blk = blockIdx.x;
    if (blk < NMAIN){
        const int ks   = threadIdx.x >> 6;
        const int lane = threadIdx.x & 63;
        const int lm   = lane & 15, lgf = lane >> 4;
        const int c    = blk * 16 + lm;
        const bool ok  = (c < N3);

        unsigned short vals[8];
        #pragma unroll
        for (int e = 0; e < 8; ++e){
            int k = ks * 32 + lgf * 8 + e;
            float v = 0.0f;
            if (ok){
                if (k < H2N)       v = W3[k * N3 + c];
                else if (k == H2N) v = b3[c];          // bias folded into K
            }
            vals[e] = f2bf(v);
        }
        *reinterpret_cast<bf16x8*>(w3f + ((size_t)(blk * 4 + ks) * 64 + lane) * 8)
            = *reinterpret_cast<bf16x8*>(vals);
    } else {
        const int p = (blk - NMAIN) * 256 + threadIdx.x;
        if (p < 976){
            if (p < TAILN){
                int j = p / 17, k = p - j * 17;
                pk[p] = ((unsigned)(idx2[j] * 17 + k) << 16) | (unsigned)(idx1[j] * 17 + k);
                pw[p] = wgt[j];
            } else { pk[p] = 0; pw[p] = 0.0f; }
        }
    }
}

__global__ __launch_bounds__(TPB, 4)
void snn_kernel(const float* __restrict__ x,
                const float* __restrict__ W1, const float* __restrict__ b1,
                const float* __restrict__ W2, const float* __restrict__ b2,
                const unsigned short* __restrict__ w3f,
                const unsigned int* __restrict__ pk,
                const float* __restrict__ pw,
                float* __restrict__ out)
{
    __shared__ __align__(16) unsigned short panel[GR][PSTRC];   // 70,784 B
    __shared__ __align__(16) unsigned short h2b[GR][KPAD];      //  4,096 B
    __shared__ float w2s[H2N * 10];                             //  4,000 B
    __shared__ float b2s[H2N];                                  //    400 B
    __shared__ float xs[RPB];                                   //  1,024 B
    __shared__ float w1s[10], b1s[10];                          //     80 B
    __shared__ __align__(16) unsigned int pks[976];             //  3,904 B
    __shared__ __align__(16) float        pws[976];             //  3,904 B
    // total ~86.1 KB -> 1 block/CU

    const int t = threadIdx.x, lane = t & 63, wid = t >> 6;     // 16 waves
    const int lm = lane & 15, lg = lane >> 4;
    const unsigned int rowblk0 = blockIdx.x * RPB;

    #define LOADFRAG(dst, tile) do {                                              \
        const unsigned short* bp_ = w3f + ((size_t)((tile) * 4) * 64 + lane) * 8; \
        _Pragma("unroll")                                                         \
        for (int ks_ = 0; ks_ < 4; ++ks_)                                         \
            dst[ks_] = *reinterpret_cast<const bf16x8*>(bp_ + (size_t)ks_ * 512); \
    } while(0)

    // ---- prologue: stage EVERYTHING (the only global loads in this kernel)
    for (int i = t; i < H2N * 10; i += TPB) w2s[i] = W2[i];
    if (t < H2N) b2s[t] = b2[t];
    if (t < 10){ w1s[t] = W1[t]; b1s[t] = b1[t]; }
    if (t < RPB) xs[t] = x[rowblk0 + t];
    if (t < 976){ pks[t] = pk[t]; pws[t] = pw[t]; }

    bf16x8 wfr[5][4];                       // W3 frags resident (80 VGPR)
    #pragma unroll
    for (int i = 0; i < 5; ++i){
        const int s = wid + (i << 4);
        if (s < NMAIN) LOADFRAG(wfr[i], s);
    }
    __syncthreads();                        // one full sync (drains prologue loads)

    // ---- 16-group steady state: 2 raw barriers/group, zero global loads
    for (int g = 0; g < NGRP; ++g){
        // ---- A: fused h1+h2 — thread owns (row r, cols c0,c0+1); no intra-phase sync
        {
            const int r  = t >> 6;
            const int c0 = (t & 63) << 1;
            const float xr = xs[(g << 4) + r];
            float h1v[10];
            #pragma unroll
            for (int j = 0; j < 10; ++j)
                h1v[j] = fast_sigmoid(xr * w1s[j] + b1s[j]);
            unsigned short o0, o1;
            if (c0 < H2N){
                float z = b2s[c0];
                #pragma unroll
                for (int j = 0; j < 10; ++j) z += h1v[j] * w2s[j * H2N + c0];
                o0 = f2bf(fast_sigmoid(z));
            } else o0 = (c0 == H2N) ? 0x3F80 : 0;          // 1.0 bias lane / zero pad
            const int c1 = c0 + 1;
            if (c1 < H2N){
                float z = b2s[c1];
                #pragma unroll
                for (int j = 0; j < 10; ++j) z += h1v[j] * w2s[j * H2N + c1];
                o1 = f2bf(fast_sigmoid(z));
            } else o1 = (c1 == H2N) ? 0x3F80 : 0;
            unsigned int packed = (unsigned)o0 | ((unsigned)o1 << 16);
            *reinterpret_cast<unsigned int*>(&h2b[r][c0]) = packed;
        }
        BAR();                                             // BAR1: h2 ready
        // ---- B: MFMA from register-resident W3 frags -> panel
        {
            bf16x8 hfr[4];
            #pragma unroll
            for (int ks = 0; ks < 4; ++ks)
                hfr[ks] = *reinterpret_cast<const bf16x8*>(&h2b[lm][ks * 32 + lg * 8]);
            #pragma unroll
            for (int i = 0; i < 5; ++i){
                const int s = wid + (i << 4);
                if (s < NMAIN){
                    f32x4 a = {0,0,0,0};
                    #pragma unroll
                    for (int ks = 0; ks < 4; ++ks)
                        a = __builtin_amdgcn_mfma_f32_16x16x32_bf16(wfr[i][ks], hfr[ks], a, 0, 0, 0);
                    unsigned short o[4];
                    #pragma unroll
                    for (int r = 0; r < 4; ++r) o[r] = f2bf(fast_sigmoid(a[r]));
                    *reinterpret_cast<u16x4*>(&panel[lm][(s << 4) + (lg << 2)]) =
                        *reinterpret_cast<u16x4*>(o);
                }
            }
        }
        BAR();                                             // BAR2: panel main cols ready
        // ---- C: per-wave row = wid — tail lerp into panel, then dump the row.
        //      Wave-local row ownership: no barrier needed between lerp and dump.
        {
            const int row = wid;
            #pragma unroll
            for (int i = 0; i < 8; ++i){
                const int p0 = (lane + (i << 6)) << 1;     // even p, pairs (p0, p0+1)
                if (p0 < TAILN){
                    const unsigned int k0 = pks[p0], k1 = pks[p0 + 1];
                    const float w0 = pws[p0], w1 = pws[p0 + 1];
                    const float a2 = bf2f(panel[row][k0 >> 16]);
                    const float a1 = bf2f(panel[row][k0 & 0xffffu]);
                    const float b2v = bf2f(panel[row][k1 >> 16]);
                    const float b1v = bf2f(panel[row][k1 & 0xffffu]);
                    const unsigned short t0 = f2bf(fmaf(w0, a1 - a2, a2));
                    const unsigned short t1 = f2bf(fmaf(w1, b1v - b2v, b2v));
                    *reinterpret_cast<unsigned int*>(&panel[row][1232 + p0]) =
                        (unsigned)t0 | ((unsigned)t1 << 16);
                }
            }
            float* orow = out + (size_t)(rowblk0 + (g << 4) + row) * OUTW;
            #pragma unroll
            for (int ch = 0; ch < 9; ++ch){
                const int rc = ch * 256 + (lane << 2);
                if (rc <= 2188){
                    const int vc = rc + (rc >= N3 ? 8 : 0);
                    const u16x4 pv = *reinterpret_cast<const u16x4*>(&panel[row][vc]);
                    f32x4 v;
                    #pragma unroll
                    for (int e = 0; e < 4; ++e) v[e] = bf2f(pv[e]);
                    store16(orow + rc, v);
                } else if (rc == 2192){
                    orow[rc] = bf2f(panel[row][rc + 8]);
                }
            }
        }
        // no barrier: next A writes h2b (safe after BAR2); next B waits BAR1'
    }
    #undef LOADFRAG
}

extern "C" void kernel_launch(void* const* d_in, const int* in_sizes, int n_in,
                              void* d_out, int out_size, void* d_ws, size_t ws_size,
                              hipStream_t stream)
{
    const float* x   = (const float*)d_in[0];
    const float* W1  = (const float*)d_in[1];
    const float* b1  = (const float*)d_in[2];
    const float* W2  = (const float*)d_in[3];
    const float* b2  = (const float*)d_in[4];
    const float* W3  = (const float*)d_in[5];
    const float* b3  = (const float*)d_in[6];
    const float* wgt = (const float*)d_in[7];
    const int*   i1  = (const int*)d_in[8];
    const int*   i2  = (const int*)d_in[9];
    float* out = (float*)d_out;

    unsigned char* ws = (unsigned char*)d_ws;
    unsigned short* w3f = (unsigned short*)ws;                 // 315,392 B
    unsigned int*   pk  = (unsigned int*)(ws + 315392);        // 3,904 B
    float*          pw  = (float*)(ws + 315392 + 3904);        // 3,904 B

    prep_kernel<<<NMAIN + 4, 256, 0, stream>>>(W3, b3, wgt, i1, i2, w3f, pk, pw);
    snn_kernel<<<NBLK, TPB, 0, stream>>>(x, W1, b1, W2, b2, w3f, pk, pw, out);
}